// Round 6
// baseline (435.947 us; speedup 1.0000x reference)
//
#include <hip/hip_runtime.h>
#include <hip/hip_bf16.h>

#define EDGES 600000
#define DIN 128
#define DHID 256
#define DOUT 128
#define NNODES 100000

#define EPB 32                  // edges per wave-chunk (2 groups of 16)
#define NCHUNK 18750            // EDGES / 32 (exact, no tail)
#define NBLK 256                // 1 block per CU (LDS-bound), single round
#define THREADS 512             // 8 waves/block -> 2 waves/SIMD
#define STRIDE 2048             // NBLK * 8 waves

// LDS map (bytes):
//   [0, 65536)        W1 frags  shortx8[(t*4+ks)*64 + lane]
//   [65536, 131072)   W2 frags  shortx8[(t*4+op)*64 + lane]  (ot-pairs packed)
//   [131072, 132096)  b1 (256 f32)
//   [132096, 132608)  b2 (128 f32)
#define W2_OFF 65536
#define B1_OFF 131072
#define B2_OFF 132096
#define LDS_BYTES 132608

// ws (shorts): [0,32768) W1 frags, [32768,65536) W2 frags,
//              [65536, 65536+12800000) x in bf16 (25.6 MB, L3-resident)
#define XB_OFF_SHORTS 65536
#define WS_BYTES_NEEDED (131072ull + (unsigned long long)NNODES * DIN * 2ull)

typedef __attribute__((ext_vector_type(4))) float floatx4;
typedef __attribute__((ext_vector_type(4))) short shortx4;
typedef __attribute__((ext_vector_type(8))) short shortx8;

__device__ inline unsigned short f2bf_rne(float f) {
    union { float f; unsigned u; } v; v.f = f;
    unsigned r = v.u + 0x7FFFu + ((v.u >> 16) & 1u);
    return (unsigned short)(r >> 16);
}

// Pre-pass: convert W1/W2 fp32 -> bf16, swizzled fragment-major.
// W1s: frag (t,ks): 64 lanes x 8 bf16  (A-frag of 16x16x32: m=lane&15, k=q*8+j)
// W2s: frag (t,op): 64 lanes x 8 bf16 = ot-PAIR: lower 4 = A-frag of ot=2op,
//      upper 4 = A-frag of ot=2op+1 (16x16x16: m=lane&15, k=q*4+j)
//      -> gin reads one ds_read_b128 per ot-pair instead of 2x ds_read_b64.
__global__ __launch_bounds__(256) void prep_kernel(
        const float* __restrict__ W1, const float* __restrict__ W2,
        unsigned short* __restrict__ ws) {
    int j = blockIdx.x * 256 + threadIdx.x;
    if (j < 4096) {                       // W1 frags: 16 t * 4 ks * 64 lanes
        int lane = j & 63, fs = j >> 6;
        int ks = fs & 3, t = fs >> 2;
        int hid = t * 16 + (lane & 15), q = lane >> 4;
        const float* src = W1 + hid * DIN + ks * 32 + q * 8;
        shortx8 v;
        #pragma unroll
        for (int i = 0; i < 8; ++i) v[i] = (short)f2bf_rne(src[i]);
        *((shortx8*)ws + j) = v;
    } else if (j < 8192) {                // W2 pair-frags: 16 t * 4 op * 64 lanes
        int j2 = j - 4096;
        int lane = j2 & 63, fs = j2 >> 6;
        int op = fs & 3, t = fs >> 2;
        int m = lane & 15, q = lane >> 4;
        const float* lo = W2 + (size_t)(op * 32 + m) * DHID + t * 16 + q * 4;
        const float* hi = W2 + (size_t)(op * 32 + 16 + m) * DHID + t * 16 + q * 4;
        shortx8 v;
        #pragma unroll
        for (int i = 0; i < 4; ++i) {
            v[i]     = (short)f2bf_rne(lo[i]);
            v[4 + i] = (short)f2bf_rne(hi[i]);
        }
        *((shortx8*)(ws + 32768) + j2) = v;
    }
}

// Pre-pass: x fp32 -> bf16 (25.6 MB working set -> gathers become L3 hits
// and read half the bytes).
__global__ __launch_bounds__(256) void prep_x(
        const float* __restrict__ x, unsigned short* __restrict__ xb) {
    const int total = NNODES * DIN / 4;   // 3.2M float4
    for (int i = blockIdx.x * 256 + threadIdx.x; i < total; i += gridDim.x * 256) {
        float4 v = ((const float4*)x)[i];
        shortx4 o;
        o[0] = (short)f2bf_rne(v.x); o[1] = (short)f2bf_rne(v.y);
        o[2] = (short)f2bf_rne(v.z); o[3] = (short)f2bf_rne(v.w);
        *((shortx4*)xb + i) = o;
    }
}

// Per-wave pipelined fused kernel. Each wave owns 32-edge chunks (2 groups
// of 16 edges share every weight-fragment LDS read -> per-edge LDS traffic
// halved vs 16-edge chunks; LDS pipe drops below the MFMA pipe).
// Per chunk: convert raw -> sfrag[2][4]; issue next chunk's gather (completes
// under MFMA); per t: a1 = 4x ds_read_b128, GEMM1 both groups, relu+bias+bf16
// in regs, GEMM2 via 4x ds_read_b128 ot-pairs for both groups; epilogue
// 16 float4 stores. Weights+biases in LDS -> MFMA loop has zero vmem ops.
template <bool BFX>
__global__ __launch_bounds__(THREADS, 2) void gin_kernel(
        const float* __restrict__ x, const unsigned short* __restrict__ xb,
        const int* __restrict__ ei,
        const float* __restrict__ b1, const float* __restrict__ b2,
        const unsigned short* __restrict__ wsw,
        float* __restrict__ out) {
    extern __shared__ char smem[];
    const int tid = threadIdx.x;
    const int lane = tid & 63, q = lane >> 4, col = lane & 15;

    const int gw = blockIdx.x * 8 + (tid >> 6);   // < 2048 <= NCHUNK: valid
    int ch = gw;

    shortx8 rawb[2][8];   // [group][2 rows x 4 ks], bf16 endpoint slices

    auto gather = [&](const int* na, const int* nb) {
        #pragma unroll
        for (int g = 0; g < 2; ++g) {
            if constexpr (BFX) {
                const shortx8* pa = (const shortx8*)xb + (size_t)na[g] * 16 + q;
                const shortx8* pb = (const shortx8*)xb + (size_t)nb[g] * 16 + q;
                #pragma unroll
                for (int ks = 0; ks < 4; ++ks) {
                    rawb[g][ks*2+0] = pa[ks*4];
                    rawb[g][ks*2+1] = pb[ks*4];
                }
            } else {
                const float* pa = x + (size_t)na[g] * DIN + q * 8;
                const float* pb = x + (size_t)nb[g] * DIN + q * 8;
                #pragma unroll
                for (int ks = 0; ks < 4; ++ks) {
                    float4 u0 = *(const float4*)(pa + ks*32);
                    float4 u1 = *(const float4*)(pa + ks*32 + 4);
                    float4 v0 = *(const float4*)(pb + ks*32);
                    float4 v1 = *(const float4*)(pb + ks*32 + 4);
                    shortx8 sa, sb;
                    sa[0]=(short)f2bf_rne(u0.x); sa[1]=(short)f2bf_rne(u0.y);
                    sa[2]=(short)f2bf_rne(u0.z); sa[3]=(short)f2bf_rne(u0.w);
                    sa[4]=(short)f2bf_rne(u1.x); sa[5]=(short)f2bf_rne(u1.y);
                    sa[6]=(short)f2bf_rne(u1.z); sa[7]=(short)f2bf_rne(u1.w);
                    sb[0]=(short)f2bf_rne(v0.x); sb[1]=(short)f2bf_rne(v0.y);
                    sb[2]=(short)f2bf_rne(v0.z); sb[3]=(short)f2bf_rne(v0.w);
                    sb[4]=(short)f2bf_rne(v1.x); sb[5]=(short)f2bf_rne(v1.y);
                    sb[6]=(short)f2bf_rne(v1.z); sb[7]=(short)f2bf_rne(v1.w);
                    rawb[g][ks*2+0] = sa;
                    rawb[g][ks*2+1] = sb;
                }
            }
        }
    };

    auto load_ei = [&](int c, int* na, int* nb) {
        #pragma unroll
        for (int g = 0; g < 2; ++g) {
            const int e = c * EPB + g * 16 + col;
            na[g] = ei[e];
            nb[g] = ei[EDGES + e];
        }
    };

    // ---- prologue ----
    int na0[2], nb0[2], naN[2], nbN[2];
    load_ei(ch, na0, nb0);

    // weights -> LDS (131072 B = 8192 float4)
    {
        const float4* gsrc = (const float4*)wsw;
        for (int idx = tid; idx < 8192; idx += THREADS) {
            float4 v = gsrc[idx];
            *(float4*)(smem + (size_t)idx * 16) = v;
        }
        if (tid < 384) {
            float v = (tid < 256) ? b1[tid] : b2[tid - 256];
            *(float*)(smem + B1_OFF + tid * 4) = v;
        }
    }

    gather(na0, nb0);
    load_ei(ch + STRIDE < NCHUNK ? ch + STRIDE : ch, naN, nbN);
    __syncthreads();   // weights ready; no barriers after this point

    const shortx8* w1l = (const shortx8*)smem + lane;
    const shortx8* w2l = (const shortx8*)(smem + W2_OFF) + lane;
    const floatx4* b1l = (const floatx4*)(smem + B1_OFF) + q;
    const floatx4* b2l = (const floatx4*)(smem + B2_OFF) + q;

    for (;;) {
        // convert raw -> sfrag (B-frag: n=edge=col, k=ks*32+q*8+j)
        shortx8 sfrag[2][4];
        #pragma unroll
        for (int g = 0; g < 2; ++g) {
            #pragma unroll
            for (int ks = 0; ks < 4; ++ks) {
                union { shortx8 s8; __hip_bfloat162 h[4]; } A, B, S;
                A.s8 = rawb[g][ks*2]; B.s8 = rawb[g][ks*2+1];
                #pragma unroll
                for (int j = 0; j < 4; ++j) {
                    float2 fa = __bfloat1622float2(A.h[j]);
                    float2 fb = __bfloat1622float2(B.h[j]);
                    S.h[j] = __float22bfloat162_rn(make_float2(fa.x + fb.x, fa.y + fb.y));
                }
                sfrag[g][ks] = S.s8;
            }
        }

        // issue next chunk's gather NOW; it completes under the MFMA phase
        const int chN = ch + STRIDE;
        const bool haveN = (chN < NCHUNK);
        if (haveN) {
            gather(naN, nbN);
            const int ch2 = chN + STRIDE;
            if (ch2 < NCHUNK) load_ei(ch2, naN, nbN);
        }

        // ---- MFMA phase: LDS-only operand traffic ----
        floatx4 acc2[2][8];
        #pragma unroll
        for (int ot = 0; ot < 8; ++ot) {
            floatx4 bv = b2l[ot*4];
            acc2[0][ot] = bv;
            acc2[1][ot] = bv;
        }

        #pragma unroll 1
        for (int t = 0; t < 16; ++t) {
            shortx8 a1[4];
            #pragma unroll
            for (int ks = 0; ks < 4; ++ks) a1[ks] = w1l[(t*4+ks)*64];
            const floatx4 bv1 = b1l[t*4];
            floatx4 acc1[2];
            acc1[0] = bv1; acc1[1] = bv1;
            #pragma unroll
            for (int ks = 0; ks < 4; ++ks) {
                acc1[0] = __builtin_amdgcn_mfma_f32_16x16x32_bf16(a1[ks], sfrag[0][ks], acc1[0], 0, 0, 0);
                acc1[1] = __builtin_amdgcn_mfma_f32_16x16x32_bf16(a1[ks], sfrag[1][ks], acc1[1], 0, 0, 0);
            }
            shortx4 hf[2];
            #pragma unroll
            for (int g = 0; g < 2; ++g) {
                union { shortx4 s4; __hip_bfloat162 b[2]; } pk;
                pk.b[0] = __float22bfloat162_rn(make_float2(fmaxf(acc1[g][0], 0.f), fmaxf(acc1[g][1], 0.f)));
                pk.b[1] = __float22bfloat162_rn(make_float2(fmaxf(acc1[g][2], 0.f), fmaxf(acc1[g][3], 0.f)));
                hf[g] = pk.s4;
            }
            #pragma unroll
            for (int op = 0; op < 4; ++op) {
                union { shortx8 s8; shortx4 s4[2]; } w;
                w.s8 = w2l[(t*4+op)*64];
                // swapped operands: D^T, C-layout col=edge, row=outcol-frag
                acc2[0][op*2+0] = __builtin_amdgcn_mfma_f32_16x16x16bf16_1k(w.s4[0], hf[0], acc2[0][op*2+0], 0, 0, 0);
                acc2[1][op*2+0] = __builtin_amdgcn_mfma_f32_16x16x16bf16_1k(w.s4[0], hf[1], acc2[1][op*2+0], 0, 0, 0);
                acc2[0][op*2+1] = __builtin_amdgcn_mfma_f32_16x16x16bf16_1k(w.s4[1], hf[0], acc2[0][op*2+1], 0, 0, 0);
                acc2[1][op*2+1] = __builtin_amdgcn_mfma_f32_16x16x16bf16_1k(w.s4[1], hf[1], acc2[1][op*2+1], 0, 0, 0);
            }
        }

        // ---- epilogue: out[edge=ch*32+g*16+col][ot*16 + q*4 + r] = 0.5*acc2 ----
        #pragma unroll
        for (int g = 0; g < 2; ++g) {
            float* op_ = out + (size_t)(ch * EPB + g * 16 + col) * DOUT + q * 4;
            #pragma unroll
            for (int ot = 0; ot < 8; ++ot) {
                floatx4 v = acc2[g][ot] * 0.5f;
                *(floatx4*)(op_ + ot * 16) = v;
            }
        }

        if (!haveN) break;
        ch = chN;
    }
}

extern "C" void kernel_launch(void* const* d_in, const int* in_sizes, int n_in,
                              void* d_out, int out_size, void* d_ws, size_t ws_size,
                              hipStream_t stream) {
    const float* x  = (const float*)d_in[0];
    const int*   ei = (const int*)d_in[1];     // edge_index as int32 per harness
    const float* W1 = (const float*)d_in[2];
    const float* b1 = (const float*)d_in[3];
    const float* W2 = (const float*)d_in[4];
    const float* b2 = (const float*)d_in[5];
    unsigned short* ws = (unsigned short*)d_ws;

    static bool attr_done = false;
    if (!attr_done) {
        (void)hipFuncSetAttribute((const void*)gin_kernel<true>,
                                  hipFuncAttributeMaxDynamicSharedMemorySize,
                                  LDS_BYTES);
        (void)hipFuncSetAttribute((const void*)gin_kernel<false>,
                                  hipFuncAttributeMaxDynamicSharedMemorySize,
                                  LDS_BYTES);
        attr_done = true;
    }

    prep_kernel<<<48, 256, 0, stream>>>(W1, W2, ws);
    if (ws_size >= WS_BYTES_NEEDED) {
        unsigned short* xb = ws + XB_OFF_SHORTS;
        prep_x<<<2048, 256, 0, stream>>>(x, xb);
        gin_kernel<true><<<NBLK, THREADS, LDS_BYTES, stream>>>(
            x, xb, ei, b1, b2, ws, (float*)d_out);
    } else {
        gin_kernel<false><<<NBLK, THREADS, LDS_BYTES, stream>>>(
            x, nullptr, ei, b1, b2, ws, (float*)d_out);
    }
}